// Round 1
// baseline (903.158 us; speedup 1.0000x reference)
//
#include <hip/hip_runtime.h>

#define N_NODES 50000
#define N_EDGES 600000
#define IN_DIM 256
#define HID 128
#define OUT_DIM 10
#define BN_EPS 1e-5f

// ---------------- edge preprocessing: CSR by dst ----------------

__global__ void count_kernel(const int* __restrict__ dst, int* __restrict__ cnt) {
    int e = blockIdx.x * blockDim.x + threadIdx.x;
    if (e < N_EDGES) atomicAdd(&cnt[dst[e]], 1);
}

// single-block scan over 50000 degree counts -> row_ptr (exclusive), fill_ptr copy, dinv
__global__ __launch_bounds__(1024) void scan_kernel(const int* __restrict__ cnt,
                                                    int* __restrict__ row_ptr,
                                                    int* __restrict__ fill_ptr,
                                                    float* __restrict__ dinv) {
    __shared__ int wsum[16];
    const int N = N_NODES;
    int tid = threadIdx.x;
    int per = (N + 1023) >> 10;          // 49
    int beg = tid * per;
    int end = beg + per; if (end > N) end = N;
    int s = 0;
    for (int i = beg; i < end; ++i) s += cnt[i];
    int lane = tid & 63, wv = tid >> 6;
    int v = s;
    #pragma unroll
    for (int off = 1; off < 64; off <<= 1) {
        int t = __shfl_up(v, off, 64);
        if (lane >= off) v += t;
    }
    if (lane == 63) wsum[wv] = v;
    __syncthreads();
    if (wv == 0 && lane < 16) {
        int w = wsum[lane];
        #pragma unroll
        for (int off = 1; off < 16; off <<= 1) {
            int t = __shfl_up(w, off, 64);
            if (lane >= off) w += t;
        }
        wsum[lane] = w;
    }
    __syncthreads();
    int run = (wv ? wsum[wv - 1] : 0) + (v - s);   // exclusive prefix for this thread's chunk
    for (int i = beg; i < end; ++i) {
        int c = cnt[i];
        row_ptr[i] = run;
        fill_ptr[i] = run;
        dinv[i] = rsqrtf((float)c + 1.0f);         // +1 self-loop
        run += c;
    }
    if (tid == 1023) row_ptr[N] = run;
}

__global__ void fill_kernel(const int* __restrict__ src, const int* __restrict__ dst,
                            int* __restrict__ fill_ptr, int* __restrict__ col_src) {
    int e = blockIdx.x * blockDim.x + threadIdx.x;
    if (e < N_EDGES) {
        int d = dst[e];
        int p = atomicAdd(&fill_ptr[d], 1);
        col_src[p] = src[e];
    }
}

// ---------------- fp32 tiled GEMM: out[M,128] = A[M,K] @ W[K,128] (+bias)(+relu) ----------------
// 256 threads, 64x128 tile, BK=32. Each thread: 8 rows x 4 cols.

template <int RELU>
__global__ __launch_bounds__(256) void gemm128(const float* __restrict__ A,
                                               const float* __restrict__ W,
                                               const float* __restrict__ bias,
                                               float* __restrict__ out, int M, int K) {
    __shared__ float As[32][68];    // [k][m], padded
    __shared__ float Ws[32][HID];   // [k][n]
    int tid = threadIdx.x;
    int tr = tid >> 5;              // 0..7  -> rows tr*8 .. tr*8+7
    int tc = tid & 31;              // 0..31 -> cols tc*4 .. tc*4+3
    int m0 = blockIdx.x * 64;

    float acc[8][4];
    #pragma unroll
    for (int i = 0; i < 8; ++i)
        #pragma unroll
        for (int j = 0; j < 4; ++j) acc[i][j] = 0.f;

    for (int k0 = 0; k0 < K; k0 += 32) {
        #pragma unroll
        for (int it = 0; it < 2; ++it) {          // A tile: 64x32 floats = 512 float4
            int u = it * 256 + tid;
            int r = u >> 3, kq = u & 7;
            int row = m0 + r;
            float4 av = make_float4(0.f, 0.f, 0.f, 0.f);
            if (row < M) av = *(const float4*)(A + (size_t)row * K + k0 + kq * 4);
            As[kq * 4 + 0][r] = av.x;
            As[kq * 4 + 1][r] = av.y;
            As[kq * 4 + 2][r] = av.z;
            As[kq * 4 + 3][r] = av.w;
        }
        #pragma unroll
        for (int it = 0; it < 4; ++it) {          // W tile: 32x128 floats = 1024 float4
            int u = it * 256 + tid;
            int kk = u >> 5, nq = u & 31;
            *(float4*)&Ws[kk][nq * 4] = *(const float4*)(W + (size_t)(k0 + kk) * HID + nq * 4);
        }
        __syncthreads();
        #pragma unroll
        for (int k = 0; k < 32; ++k) {
            float a[8], b[4];
            #pragma unroll
            for (int i = 0; i < 8; ++i) a[i] = As[k][tr * 8 + i];
            #pragma unroll
            for (int j = 0; j < 4; ++j) b[j] = Ws[k][tc * 4 + j];
            #pragma unroll
            for (int i = 0; i < 8; ++i)
                #pragma unroll
                for (int j = 0; j < 4; ++j) acc[i][j] += a[i] * b[j];
        }
        __syncthreads();
    }

    float4 bv = make_float4(0.f, 0.f, 0.f, 0.f);
    if (bias) bv = *(const float4*)(bias + tc * 4);
    #pragma unroll
    for (int i = 0; i < 8; ++i) {
        int row = m0 + tr * 8 + i;
        if (row < M) {
            float4 o;
            o.x = acc[i][0] + bv.x;
            o.y = acc[i][1] + bv.y;
            o.z = acc[i][2] + bv.z;
            o.w = acc[i][3] + bv.w;
            if (RELU) {
                o.x = fmaxf(o.x, 0.f); o.y = fmaxf(o.y, 0.f);
                o.z = fmaxf(o.z, 0.f); o.w = fmaxf(o.w, 0.f);
            }
            *(float4*)(out + (size_t)row * HID + tc * 4) = o;
        }
    }
}

// ---------------- CSR pull aggregation ----------------
// C[n][f] = dinv[n] * ( sum_{e:dst=n} B[src_e][f]*dinv[src_e] + B[n][f]*dinv[n] ) + bc[f]

__global__ __launch_bounds__(256) void agg_kernel(const float* __restrict__ B,
                                                  const float* __restrict__ dinv,
                                                  const int* __restrict__ row_ptr,
                                                  const int* __restrict__ col_src,
                                                  const float* __restrict__ bc,
                                                  float* __restrict__ C) {
    int f = threadIdx.x;               // 0..127
    int n = blockIdx.x * 2 + threadIdx.y;
    if (n >= N_NODES) return;
    float di = dinv[n];
    float acc = B[(size_t)n * HID + f] * di;
    int beg = row_ptr[n], end = row_ptr[n + 1];
    for (int e = beg; e < end; ++e) {
        int s = col_src[e];
        acc += B[(size_t)s * HID + f] * dinv[s];
    }
    C[(size_t)n * HID + f] = acc * di + bc[f];
}

// ---------------- BN stats / finalize / apply ----------------

__global__ __launch_bounds__(256) void stats_kernel(const float* __restrict__ C,
                                                    float* __restrict__ colsum,
                                                    float* __restrict__ colsumsq) {
    __shared__ float sh[512];
    int f = threadIdx.x & 127;
    int g = threadIdx.x >> 7;
    int r0 = blockIdx.x * 100;
    float s = 0.f, sq = 0.f;
    for (int r = g; r < 100; r += 2) {
        float v = C[(size_t)(r0 + r) * HID + f];
        s += v; sq += v * v;
    }
    sh[threadIdx.x] = s;
    sh[256 + threadIdx.x] = sq;
    __syncthreads();
    if (threadIdx.x < 128) {
        s = sh[threadIdx.x] + sh[threadIdx.x + 128];
        sq = sh[256 + threadIdx.x] + sh[256 + threadIdx.x + 128];
        atomicAdd(&colsum[f], s);
        atomicAdd(&colsumsq[f], sq);
    }
}

__global__ void finalize_bn(const float* __restrict__ colsum, const float* __restrict__ colsumsq,
                            const float* __restrict__ gamma, const float* __restrict__ beta,
                            float* __restrict__ scale, float* __restrict__ shift) {
    int f = threadIdx.x;
    float mu = colsum[f] * (1.0f / N_NODES);
    float var = colsumsq[f] * (1.0f / N_NODES) - mu * mu;
    float rstd = rsqrtf(var + BN_EPS);
    float sc = rstd * gamma[f];
    scale[f] = sc;
    shift[f] = beta[f] - mu * sc;
}

template <int RES>
__global__ __launch_bounds__(256) void apply_bn(const float* __restrict__ C,
                                                const float* __restrict__ scale,
                                                const float* __restrict__ shift,
                                                float* __restrict__ A) {
    int idx = blockIdx.x * blockDim.x + threadIdx.x;   // float4 index
    const int total = N_NODES * HID / 4;
    if (idx >= total) return;
    int fq = idx & 31;                                  // 32 float4 per row
    float4 c = ((const float4*)C)[idx];
    float4 sc = ((const float4*)scale)[fq];
    float4 sh = ((const float4*)shift)[fq];
    float4 h;
    h.x = fmaxf(c.x * sc.x + sh.x, 0.f);
    h.y = fmaxf(c.y * sc.y + sh.y, 0.f);
    h.z = fmaxf(c.z * sc.z + sh.z, 0.f);
    h.w = fmaxf(c.w * sc.w + sh.w, 0.f);
    if (RES) {
        float4 a = ((const float4*)A)[idx];
        h.x += a.x; h.y += a.y; h.z += a.z; h.w += a.w;
    }
    ((float4*)A)[idx] = h;
}

// ---------------- output projection: out[M,10] = h[M,128] @ Wo[128,10] + bo ----------------

__global__ __launch_bounds__(256) void out_gemm(const float* __restrict__ h,
                                                const float* __restrict__ Wo,
                                                const float* __restrict__ bo,
                                                float* __restrict__ out) {
    __shared__ float Ws[HID * OUT_DIM];
    for (int i = threadIdx.x; i < HID * OUT_DIM; i += 256) Ws[i] = Wo[i];
    __syncthreads();
    int gid = blockIdx.x * blockDim.x + threadIdx.x;
    if (gid >= N_NODES * OUT_DIM) return;
    int n = gid / OUT_DIM;
    int c = gid - n * OUT_DIM;
    const float* hr = h + (size_t)n * HID;
    float s = 0.f;
    #pragma unroll 4
    for (int k = 0; k < HID; ++k) s += hr[k] * Ws[k * OUT_DIM + c];
    out[gid] = s + bo[c];
}

// ---------------- launch ----------------

extern "C" void kernel_launch(void* const* d_in, const int* in_sizes, int n_in,
                              void* d_out, int out_size, void* d_ws, size_t ws_size,
                              hipStream_t stream) {
    const float* x     = (const float*)d_in[0];
    const int*   ei    = (const int*)d_in[1];
    const int*   src   = ei;
    const int*   dst   = ei + N_EDGES;
    const float* W_in  = (const float*)d_in[2];
    const float* b_in  = (const float*)d_in[3];
    const float* Wc    = (const float*)d_in[4];
    const float* bc    = (const float*)d_in[5];
    const float* gamma = (const float*)d_in[6];
    const float* beta  = (const float*)d_in[7];
    const float* W_out = (const float*)d_in[8];
    const float* b_out = (const float*)d_in[9];
    float* out = (float*)d_out;

    char* p = (char*)d_ws;
    auto alloc = [&](size_t bytes) -> char* {
        char* q = p;
        p += (bytes + 255) & ~(size_t)255;
        return q;
    };
    float* A        = (float*)alloc(sizeof(float) * N_NODES * HID);   // current h (also residual)
    float* B        = (float*)alloc(sizeof(float) * N_NODES * HID);   // h @ Wc
    float* C        = (float*)alloc(sizeof(float) * N_NODES * HID);   // aggregated
    float* dinv     = (float*)alloc(sizeof(float) * N_NODES);
    int*   deg_cnt  = (int*)alloc(sizeof(int) * N_NODES);
    int*   row_ptr  = (int*)alloc(sizeof(int) * (N_NODES + 1));
    int*   fill_ptr = (int*)alloc(sizeof(int) * N_NODES);
    int*   col_src  = (int*)alloc(sizeof(int) * N_EDGES);
    float* colsum   = (float*)alloc(sizeof(float) * 256);             // [0:128) sum, [128:256) sumsq
    float* colsumsq = colsum + 128;
    float* scale    = (float*)alloc(sizeof(float) * 128);
    float* shift    = (float*)alloc(sizeof(float) * 128);

    // CSR build
    hipMemsetAsync(deg_cnt, 0, sizeof(int) * N_NODES, stream);
    count_kernel<<<(N_EDGES + 255) / 256, 256, 0, stream>>>(dst, deg_cnt);
    scan_kernel<<<1, 1024, 0, stream>>>(deg_cnt, row_ptr, fill_ptr, dinv);
    fill_kernel<<<(N_EDGES + 255) / 256, 256, 0, stream>>>(src, dst, fill_ptr, col_src);

    // input projection + relu
    gemm128<1><<<(N_NODES + 63) / 64, 256, 0, stream>>>(x, W_in, b_in, A, N_NODES, IN_DIM);

    for (int l = 0; l < 3; ++l) {
        gemm128<0><<<(N_NODES + 63) / 64, 256, 0, stream>>>(A, Wc + l * HID * HID, nullptr, B, N_NODES, HID);
        agg_kernel<<<N_NODES / 2, dim3(128, 2), 0, stream>>>(B, dinv, row_ptr, col_src, bc + l * HID, C);
        hipMemsetAsync(colsum, 0, sizeof(float) * 256, stream);
        stats_kernel<<<500, 256, 0, stream>>>(C, colsum, colsumsq);
        finalize_bn<<<1, 128, 0, stream>>>(colsum, colsumsq, gamma + l * HID, beta + l * HID, scale, shift);
        if (l == 0) apply_bn<0><<<N_NODES * HID / 4 / 256, 256, 0, stream>>>(C, scale, shift, A);
        else        apply_bn<1><<<N_NODES * HID / 4 / 256, 256, 0, stream>>>(C, scale, shift, A);
    }

    out_gemm<<<(N_NODES * OUT_DIM + 255) / 256, 256, 0, stream>>>(A, W_out, b_out, out);
}

// Round 3
// 785.450 us; speedup vs baseline: 1.1499x; 1.1499x over previous
//
#include <hip/hip_runtime.h>

#define N_NODES 50000
#define N_EDGES 600000
#define IN_DIM 256
#define HID 128
#define OUT_DIM 10
#define BN_EPS 1e-5f

// ---------------- edge preprocessing: CSR by dst (no prefix scan needed) ----------------

__global__ void count_kernel(const int* __restrict__ dst, int* __restrict__ cnt) {
    int e = blockIdx.x * blockDim.x + threadIdx.x;
    if (e < N_EDGES) atomicAdd(&cnt[dst[e]], 1);
}

// Each dst gets a contiguous disjoint range in col_src; range order is irrelevant.
// Wave-64 inclusive scan of counts, one atomicAdd on a global cursor per wave.
__global__ __launch_bounds__(256) void assign_kernel(const int* __restrict__ cnt,
                                                     int* __restrict__ row_start,
                                                     int* __restrict__ fill_ptr,
                                                     float* __restrict__ dinv,
                                                     int* __restrict__ cursor) {
    int i = blockIdx.x * blockDim.x + threadIdx.x;
    int c = (i < N_NODES) ? cnt[i] : 0;
    int lane = threadIdx.x & 63;
    int v = c;
    #pragma unroll
    for (int off = 1; off < 64; off <<= 1) {
        int t = __shfl_up(v, off, 64);
        if (lane >= off) v += t;
    }
    int waveTotal = __shfl(v, 63, 64);
    int base = 0;
    if (lane == 63) base = atomicAdd(cursor, waveTotal);
    base = __shfl(base, 63, 64);
    if (i < N_NODES) {
        int start = base + v - c;   // exclusive prefix within wave + wave base
        row_start[i] = start;
        fill_ptr[i] = start;
        dinv[i] = rsqrtf((float)c + 1.0f);   // +1 self-loop
    }
}

__global__ void fill_kernel(const int* __restrict__ src, const int* __restrict__ dst,
                            int* __restrict__ fill_ptr, int* __restrict__ col_src) {
    int e = blockIdx.x * blockDim.x + threadIdx.x;
    if (e < N_EDGES) {
        int d = dst[e];
        int p = atomicAdd(&fill_ptr[d], 1);
        col_src[p] = src[e];
    }
}

// ---------------- fp32 tiled GEMM: out[M,128] = (A[M,K] @ W[K,128]) * rowscale[m] (+bias)(+relu) ----------------
// 256 threads, 64x128 tile, BK=32. Each thread: 8 rows x 4 cols.

template <int RELU>
__global__ __launch_bounds__(256) void gemm128(const float* __restrict__ A,
                                               const float* __restrict__ W,
                                               const float* __restrict__ bias,
                                               const float* __restrict__ rowscale,
                                               float* __restrict__ out, int M, int K) {
    __shared__ float As[32][68];    // [k][m], padded
    __shared__ float Ws[32][HID];   // [k][n]
    int tid = threadIdx.x;
    int tr = tid >> 5;              // 0..7  -> rows tr*8 .. tr*8+7
    int tc = tid & 31;              // 0..31 -> cols tc*4 .. tc*4+3
    int m0 = blockIdx.x * 64;

    float acc[8][4];
    #pragma unroll
    for (int i = 0; i < 8; ++i)
        #pragma unroll
        for (int j = 0; j < 4; ++j) acc[i][j] = 0.f;

    for (int k0 = 0; k0 < K; k0 += 32) {
        #pragma unroll
        for (int it = 0; it < 2; ++it) {          // A tile: 64x32 floats = 512 float4
            int u = it * 256 + tid;
            int r = u >> 3, kq = u & 7;
            int row = m0 + r;
            float4 av = make_float4(0.f, 0.f, 0.f, 0.f);
            if (row < M) av = *(const float4*)(A + (size_t)row * K + k0 + kq * 4);
            As[kq * 4 + 0][r] = av.x;
            As[kq * 4 + 1][r] = av.y;
            As[kq * 4 + 2][r] = av.z;
            As[kq * 4 + 3][r] = av.w;
        }
        #pragma unroll
        for (int it = 0; it < 4; ++it) {          // W tile: 32x128 floats = 1024 float4
            int u = it * 256 + tid;
            int kk = u >> 5, nq = u & 31;
            *(float4*)&Ws[kk][nq * 4] = *(const float4*)(W + (size_t)(k0 + kk) * HID + nq * 4);
        }
        __syncthreads();
        #pragma unroll
        for (int k = 0; k < 32; ++k) {
            float a[8], b[4];
            #pragma unroll
            for (int i = 0; i < 8; ++i) a[i] = As[k][tr * 8 + i];
            #pragma unroll
            for (int j = 0; j < 4; ++j) b[j] = Ws[k][tc * 4 + j];
            #pragma unroll
            for (int i = 0; i < 8; ++i)
                #pragma unroll
                for (int j = 0; j < 4; ++j) acc[i][j] += a[i] * b[j];
        }
        __syncthreads();
    }

    float4 bv = make_float4(0.f, 0.f, 0.f, 0.f);
    if (bias) bv = *(const float4*)(bias + tc * 4);
    #pragma unroll
    for (int i = 0; i < 8; ++i) {
        int row = m0 + tr * 8 + i;
        if (row < M) {
            float rs = rowscale ? rowscale[row] : 1.0f;
            float4 o;
            o.x = acc[i][0] * rs + bv.x;
            o.y = acc[i][1] * rs + bv.y;
            o.z = acc[i][2] * rs + bv.z;
            o.w = acc[i][3] * rs + bv.w;
            if (RELU) {
                o.x = fmaxf(o.x, 0.f); o.y = fmaxf(o.y, 0.f);
                o.z = fmaxf(o.z, 0.f); o.w = fmaxf(o.w, 0.f);
            }
            *(float4*)(out + (size_t)row * HID + tc * 4) = o;
        }
    }
}

// ---------------- CSR pull aggregation ----------------
// Bs is pre-scaled by dinv[row]. C[n][f] = dinv[n] * ( Bs[n][f] + sum_e Bs[src_e][f] ) + bc[f]

__global__ __launch_bounds__(256) void agg_kernel(const float* __restrict__ Bs,
                                                  const float* __restrict__ dinv,
                                                  const int* __restrict__ row_start,
                                                  const int* __restrict__ cnt,
                                                  const int* __restrict__ col_src,
                                                  const float* __restrict__ bc,
                                                  float* __restrict__ C) {
    int f = threadIdx.x;               // 0..127
    int n = blockIdx.x * 2 + threadIdx.y;
    if (n >= N_NODES) return;
    float acc = Bs[(size_t)n * HID + f];
    int beg = row_start[n], end = beg + cnt[n];
    for (int e = beg; e < end; ++e) {
        int s = col_src[e];
        acc += Bs[(size_t)s * HID + f];
    }
    C[(size_t)n * HID + f] = acc * dinv[n] + bc[f];
}

// ---------------- BN stats / finalize / apply ----------------

__global__ __launch_bounds__(256) void stats_kernel(const float* __restrict__ C,
                                                    float* __restrict__ colsum,
                                                    float* __restrict__ colsumsq) {
    __shared__ float sh[512];
    int f = threadIdx.x & 127;
    int g = threadIdx.x >> 7;
    int r0 = blockIdx.x * 100;
    float s = 0.f, sq = 0.f;
    for (int r = g; r < 100; r += 2) {
        float v = C[(size_t)(r0 + r) * HID + f];
        s += v; sq += v * v;
    }
    sh[threadIdx.x] = s;
    sh[256 + threadIdx.x] = sq;
    __syncthreads();
    if (threadIdx.x < 128) {
        s = sh[threadIdx.x] + sh[threadIdx.x + 128];
        sq = sh[256 + threadIdx.x] + sh[256 + threadIdx.x + 128];
        atomicAdd(&colsum[f], s);
        atomicAdd(&colsumsq[f], sq);
    }
}

__global__ void finalize_bn(const float* __restrict__ colsum, const float* __restrict__ colsumsq,
                            const float* __restrict__ gamma, const float* __restrict__ beta,
                            float* __restrict__ scale, float* __restrict__ shift) {
    int f = threadIdx.x;
    float mu = colsum[f] * (1.0f / N_NODES);
    float var = colsumsq[f] * (1.0f / N_NODES) - mu * mu;
    float rstd = rsqrtf(var + BN_EPS);
    float sc = rstd * gamma[f];
    scale[f] = sc;
    shift[f] = beta[f] - mu * sc;
}

template <int RES>
__global__ __launch_bounds__(256) void apply_bn(const float* __restrict__ C,
                                                const float* __restrict__ scale,
                                                const float* __restrict__ shift,
                                                float* __restrict__ A) {
    int idx = blockIdx.x * blockDim.x + threadIdx.x;   // float4 index
    const int total = N_NODES * HID / 4;
    if (idx >= total) return;
    int fq = idx & 31;                                  // 32 float4 per row
    float4 c = ((const float4*)C)[idx];
    float4 sc = ((const float4*)scale)[fq];
    float4 sh = ((const float4*)shift)[fq];
    float4 h;
    h.x = fmaxf(c.x * sc.x + sh.x, 0.f);
    h.y = fmaxf(c.y * sc.y + sh.y, 0.f);
    h.z = fmaxf(c.z * sc.z + sh.z, 0.f);
    h.w = fmaxf(c.w * sc.w + sh.w, 0.f);
    if (RES) {
        float4 a = ((const float4*)A)[idx];
        h.x += a.x; h.y += a.y; h.z += a.z; h.w += a.w;
    }
    ((float4*)A)[idx] = h;
}

// ---------------- output projection: out[M,10] = h[M,128] @ Wo[128,10] + bo ----------------

__global__ __launch_bounds__(256) void out_gemm(const float* __restrict__ h,
                                                const float* __restrict__ Wo,
                                                const float* __restrict__ bo,
                                                float* __restrict__ out) {
    __shared__ float Ws[HID * OUT_DIM];
    for (int i = threadIdx.x; i < HID * OUT_DIM; i += 256) Ws[i] = Wo[i];
    __syncthreads();
    int gid = blockIdx.x * blockDim.x + threadIdx.x;
    if (gid >= N_NODES * OUT_DIM) return;
    int n = gid / OUT_DIM;
    int c = gid - n * OUT_DIM;
    const float* hr = h + (size_t)n * HID;
    float s = 0.f;
    #pragma unroll 4
    for (int k = 0; k < HID; ++k) s += hr[k] * Ws[k * OUT_DIM + c];
    out[gid] = s + bo[c];
}

// ---------------- launch ----------------

extern "C" void kernel_launch(void* const* d_in, const int* in_sizes, int n_in,
                              void* d_out, int out_size, void* d_ws, size_t ws_size,
                              hipStream_t stream) {
    const float* x     = (const float*)d_in[0];
    const int*   ei    = (const int*)d_in[1];
    const int*   src   = ei;
    const int*   dst   = ei + N_EDGES;
    const float* W_in  = (const float*)d_in[2];
    const float* b_in  = (const float*)d_in[3];
    const float* Wc    = (const float*)d_in[4];
    const float* bc    = (const float*)d_in[5];
    const float* gamma = (const float*)d_in[6];
    const float* beta  = (const float*)d_in[7];
    const float* W_out = (const float*)d_in[8];
    const float* b_out = (const float*)d_in[9];
    float* out = (float*)d_out;

    char* p = (char*)d_ws;
    auto alloc = [&](size_t bytes) -> char* {
        char* q = p;
        p += (bytes + 255) & ~(size_t)255;
        return q;
    };
    float* A         = (float*)alloc(sizeof(float) * N_NODES * HID);   // current h (also residual)
    float* B         = (float*)alloc(sizeof(float) * N_NODES * HID);   // (h @ Wc) * dinv[row]
    float* C         = (float*)alloc(sizeof(float) * N_NODES * HID);   // aggregated
    float* dinv      = (float*)alloc(sizeof(float) * N_NODES);
    int*   deg_cnt   = (int*)alloc(sizeof(int) * (N_NODES + 1));       // last int = cursor
    int*   cursor    = deg_cnt + N_NODES;
    int*   row_start = (int*)alloc(sizeof(int) * N_NODES);
    int*   fill_ptr  = (int*)alloc(sizeof(int) * N_NODES);
    int*   col_src   = (int*)alloc(sizeof(int) * N_EDGES);
    float* colsum    = (float*)alloc(sizeof(float) * 256);             // [0:128) sum, [128:256) sumsq
    float* colsumsq  = colsum + 128;
    float* scale     = (float*)alloc(sizeof(float) * 128);
    float* shift     = (float*)alloc(sizeof(float) * 128);

    // CSR build: count -> per-wave atomic range assignment -> fill
    hipMemsetAsync(deg_cnt, 0, sizeof(int) * (N_NODES + 1), stream);
    count_kernel<<<(N_EDGES + 255) / 256, 256, 0, stream>>>(dst, deg_cnt);
    assign_kernel<<<(N_NODES + 255) / 256, 256, 0, stream>>>(deg_cnt, row_start, fill_ptr, dinv, cursor);
    fill_kernel<<<(N_EDGES + 255) / 256, 256, 0, stream>>>(src, dst, fill_ptr, col_src);

    // input projection + relu
    gemm128<1><<<(N_NODES + 63) / 64, 256, 0, stream>>>(x, W_in, b_in, nullptr, A, N_NODES, IN_DIM);

    for (int l = 0; l < 3; ++l) {
        gemm128<0><<<(N_NODES + 63) / 64, 256, 0, stream>>>(A, Wc + l * HID * HID, nullptr, dinv, B, N_NODES, HID);
        agg_kernel<<<N_NODES / 2, dim3(128, 2), 0, stream>>>(B, dinv, row_start, deg_cnt, col_src, bc + l * HID, C);
        hipMemsetAsync(colsum, 0, sizeof(float) * 256, stream);
        stats_kernel<<<500, 256, 0, stream>>>(C, colsum, colsumsq);
        finalize_bn<<<1, 128, 0, stream>>>(colsum, colsumsq, gamma + l * HID, beta + l * HID, scale, shift);
        if (l == 0) apply_bn<0><<<N_NODES * HID / 4 / 256, 256, 0, stream>>>(C, scale, shift, A);
        else        apply_bn<1><<<N_NODES * HID / 4 / 256, 256, 0, stream>>>(C, scale, shift, A);
    }

    out_gemm<<<(N_NODES * OUT_DIM + 255) / 256, 256, 0, stream>>>(A, W_out, b_out, out);
}

// Round 4
// 539.598 us; speedup vs baseline: 1.6738x; 1.4556x over previous
//
#include <hip/hip_runtime.h>

#define N_NODES 50000
#define N_EDGES 600000
#define IN_DIM 256
#define HID 128
#define OUT_DIM 10
#define BN_EPS 1e-5f

typedef unsigned int uint32;
typedef unsigned short ushort16;

__device__ __forceinline__ unsigned short f2bf_rne(float f) {
    uint32 u = __float_as_uint(f);
    u += 0x7FFF + ((u >> 16) & 1);          // round-to-nearest-even
    return (unsigned short)(u >> 16);
}

// ---------------- edge preprocessing: CSR by dst (no prefix scan needed) ----------------

__global__ void count_kernel(const int* __restrict__ dst, int* __restrict__ cnt) {
    int e = blockIdx.x * blockDim.x + threadIdx.x;
    if (e < N_EDGES) atomicAdd(&cnt[dst[e]], 1);
}

// Each dst gets a contiguous disjoint range in col_src; range order is irrelevant.
// Wave-64 inclusive scan of counts, one atomicAdd on a global cursor per wave.
__global__ __launch_bounds__(256) void assign_kernel(const int* __restrict__ cnt,
                                                     int* __restrict__ row_start,
                                                     int* __restrict__ fill_ptr,
                                                     float* __restrict__ dinv,
                                                     int* __restrict__ cursor) {
    int i = blockIdx.x * blockDim.x + threadIdx.x;
    int c = (i < N_NODES) ? cnt[i] : 0;
    int lane = threadIdx.x & 63;
    int v = c;
    #pragma unroll
    for (int off = 1; off < 64; off <<= 1) {
        int t = __shfl_up(v, off, 64);
        if (lane >= off) v += t;
    }
    int waveTotal = __shfl(v, 63, 64);
    int base = 0;
    if (lane == 63) base = atomicAdd(cursor, waveTotal);
    base = __shfl(base, 63, 64);
    if (i < N_NODES) {
        int start = base + v - c;   // exclusive prefix within wave + wave base
        row_start[i] = start;
        fill_ptr[i] = start;
        dinv[i] = rsqrtf((float)c + 1.0f);   // +1 self-loop
    }
}

__global__ void fill_kernel(const int* __restrict__ src, const int* __restrict__ dst,
                            int* __restrict__ fill_ptr, int* __restrict__ col_src) {
    int e = blockIdx.x * blockDim.x + threadIdx.x;
    if (e < N_EDGES) {
        int d = dst[e];
        int p = atomicAdd(&fill_ptr[d], 1);
        col_src[p] = src[e];
    }
}

// ---------------- fp32 tiled GEMM: out[M,128] = (A[M,K] @ W[K,128]) * rowscale[m] (+bias)(+relu) ----------------
// 256 threads, 64x128 tile, BK=32. Each thread: 8 rows x 4 cols.
// OUTBF16: store as bf16 (RNE) instead of fp32.

template <int RELU, int OUTBF16>
__global__ __launch_bounds__(256) void gemm128(const float* __restrict__ A,
                                               const float* __restrict__ W,
                                               const float* __restrict__ bias,
                                               const float* __restrict__ rowscale,
                                               void* __restrict__ out_v, int M, int K) {
    __shared__ float As[32][68];    // [k][m], padded
    __shared__ float Ws[32][HID];   // [k][n]
    int tid = threadIdx.x;
    int tr = tid >> 5;              // 0..7  -> rows tr*8 .. tr*8+7
    int tc = tid & 31;              // 0..31 -> cols tc*4 .. tc*4+3
    int m0 = blockIdx.x * 64;

    float acc[8][4];
    #pragma unroll
    for (int i = 0; i < 8; ++i)
        #pragma unroll
        for (int j = 0; j < 4; ++j) acc[i][j] = 0.f;

    for (int k0 = 0; k0 < K; k0 += 32) {
        #pragma unroll
        for (int it = 0; it < 2; ++it) {          // A tile: 64x32 floats = 512 float4
            int u = it * 256 + tid;
            int r = u >> 3, kq = u & 7;
            int row = m0 + r;
            float4 av = make_float4(0.f, 0.f, 0.f, 0.f);
            if (row < M) av = *(const float4*)(A + (size_t)row * K + k0 + kq * 4);
            As[kq * 4 + 0][r] = av.x;
            As[kq * 4 + 1][r] = av.y;
            As[kq * 4 + 2][r] = av.z;
            As[kq * 4 + 3][r] = av.w;
        }
        #pragma unroll
        for (int it = 0; it < 4; ++it) {          // W tile: 32x128 floats = 1024 float4
            int u = it * 256 + tid;
            int kk = u >> 5, nq = u & 31;
            *(float4*)&Ws[kk][nq * 4] = *(const float4*)(W + (size_t)(k0 + kk) * HID + nq * 4);
        }
        __syncthreads();
        #pragma unroll
        for (int k = 0; k < 32; ++k) {
            float a[8], b[4];
            #pragma unroll
            for (int i = 0; i < 8; ++i) a[i] = As[k][tr * 8 + i];
            #pragma unroll
            for (int j = 0; j < 4; ++j) b[j] = Ws[k][tc * 4 + j];
            #pragma unroll
            for (int i = 0; i < 8; ++i)
                #pragma unroll
                for (int j = 0; j < 4; ++j) acc[i][j] += a[i] * b[j];
        }
        __syncthreads();
    }

    float4 bv = make_float4(0.f, 0.f, 0.f, 0.f);
    if (bias) bv = *(const float4*)(bias + tc * 4);
    #pragma unroll
    for (int i = 0; i < 8; ++i) {
        int row = m0 + tr * 8 + i;
        if (row < M) {
            float rs = rowscale ? rowscale[row] : 1.0f;
            float o0 = acc[i][0] * rs + bv.x;
            float o1 = acc[i][1] * rs + bv.y;
            float o2 = acc[i][2] * rs + bv.z;
            float o3 = acc[i][3] * rs + bv.w;
            if (RELU) {
                o0 = fmaxf(o0, 0.f); o1 = fmaxf(o1, 0.f);
                o2 = fmaxf(o2, 0.f); o3 = fmaxf(o3, 0.f);
            }
            if (OUTBF16) {
                ushort4 pk;
                pk.x = f2bf_rne(o0); pk.y = f2bf_rne(o1);
                pk.z = f2bf_rne(o2); pk.w = f2bf_rne(o3);
                *(ushort4*)((unsigned short*)out_v + (size_t)row * HID + tc * 4) = pk;
            } else {
                float4 o = make_float4(o0, o1, o2, o3);
                *(float4*)((float*)out_v + (size_t)row * HID + tc * 4) = o;
            }
        }
    }
}

// ---------------- CSR pull aggregation (bf16 messages, one wave per node) ----------------
// Bs rows: 128 bf16 (256 B), pre-scaled by dinv[row].
// C[n][f] = dinv[n] * ( Bs[n][f] + sum_e Bs[src_e][f] ) + bc[f]
// block (64,4): wave = one node; thread f2 handles features 2*f2, 2*f2+1 via one uint gather.

__global__ __launch_bounds__(256) void agg_kernel(const uint32* __restrict__ Bs32,  // [N][64] uints
                                                  const float* __restrict__ dinv,
                                                  const int* __restrict__ row_start,
                                                  const int* __restrict__ cnt,
                                                  const int* __restrict__ col_src,
                                                  const float* __restrict__ bc,
                                                  float* __restrict__ C) {
    int f2 = threadIdx.x;                       // 0..63
    int n = blockIdx.x * 4 + threadIdx.y;
    if (n >= N_NODES) return;

    uint32 vs = Bs32[(size_t)n * 64 + f2];      // self term
    float acc0 = __uint_as_float(vs << 16);
    float acc1 = __uint_as_float(vs & 0xFFFF0000u);

    int beg = row_start[n];
    int end = beg + cnt[n];
    int e = beg;
    for (; e + 4 <= end; e += 4) {
        int s0 = col_src[e + 0];
        int s1 = col_src[e + 1];
        int s2 = col_src[e + 2];
        int s3 = col_src[e + 3];
        uint32 v0 = Bs32[(size_t)s0 * 64 + f2];
        uint32 v1 = Bs32[(size_t)s1 * 64 + f2];
        uint32 v2 = Bs32[(size_t)s2 * 64 + f2];
        uint32 v3 = Bs32[(size_t)s3 * 64 + f2];
        acc0 += __uint_as_float(v0 << 16);
        acc1 += __uint_as_float(v0 & 0xFFFF0000u);
        acc0 += __uint_as_float(v1 << 16);
        acc1 += __uint_as_float(v1 & 0xFFFF0000u);
        acc0 += __uint_as_float(v2 << 16);
        acc1 += __uint_as_float(v2 & 0xFFFF0000u);
        acc0 += __uint_as_float(v3 << 16);
        acc1 += __uint_as_float(v3 & 0xFFFF0000u);
    }
    for (; e < end; ++e) {
        int s = col_src[e];
        uint32 v = Bs32[(size_t)s * 64 + f2];
        acc0 += __uint_as_float(v << 16);
        acc1 += __uint_as_float(v & 0xFFFF0000u);
    }

    float di = dinv[n];
    float2 bcv = *(const float2*)(bc + f2 * 2);
    float2 o;
    o.x = acc0 * di + bcv.x;
    o.y = acc1 * di + bcv.y;
    *(float2*)(C + (size_t)n * HID + f2 * 2) = o;
}

// ---------------- BN stats / finalize / apply ----------------

__global__ __launch_bounds__(256) void stats_kernel(const float* __restrict__ C,
                                                    float* __restrict__ colsum,
                                                    float* __restrict__ colsumsq) {
    __shared__ float sh[512];
    int f = threadIdx.x & 127;
    int g = threadIdx.x >> 7;
    int r0 = blockIdx.x * 100;
    float s = 0.f, sq = 0.f;
    for (int r = g; r < 100; r += 2) {
        float v = C[(size_t)(r0 + r) * HID + f];
        s += v; sq += v * v;
    }
    sh[threadIdx.x] = s;
    sh[256 + threadIdx.x] = sq;
    __syncthreads();
    if (threadIdx.x < 128) {
        s = sh[threadIdx.x] + sh[threadIdx.x + 128];
        sq = sh[256 + threadIdx.x] + sh[256 + threadIdx.x + 128];
        atomicAdd(&colsum[f], s);
        atomicAdd(&colsumsq[f], sq);
    }
}

__global__ void finalize_bn(const float* __restrict__ colsum, const float* __restrict__ colsumsq,
                            const float* __restrict__ gamma, const float* __restrict__ beta,
                            float* __restrict__ scale, float* __restrict__ shift) {
    int f = threadIdx.x;
    float mu = colsum[f] * (1.0f / N_NODES);
    float var = colsumsq[f] * (1.0f / N_NODES) - mu * mu;
    float rstd = rsqrtf(var + BN_EPS);
    float sc = rstd * gamma[f];
    scale[f] = sc;
    shift[f] = beta[f] - mu * sc;
}

template <int RES>
__global__ __launch_bounds__(256) void apply_bn(const float* __restrict__ C,
                                                const float* __restrict__ scale,
                                                const float* __restrict__ shift,
                                                float* __restrict__ A) {
    int idx = blockIdx.x * blockDim.x + threadIdx.x;   // float4 index
    const int total = N_NODES * HID / 4;
    if (idx >= total) return;
    int fq = idx & 31;                                  // 32 float4 per row
    float4 c = ((const float4*)C)[idx];
    float4 sc = ((const float4*)scale)[fq];
    float4 sh = ((const float4*)shift)[fq];
    float4 h;
    h.x = fmaxf(c.x * sc.x + sh.x, 0.f);
    h.y = fmaxf(c.y * sc.y + sh.y, 0.f);
    h.z = fmaxf(c.z * sc.z + sh.z, 0.f);
    h.w = fmaxf(c.w * sc.w + sh.w, 0.f);
    if (RES) {
        float4 a = ((const float4*)A)[idx];
        h.x += a.x; h.y += a.y; h.z += a.z; h.w += a.w;
    }
    ((float4*)A)[idx] = h;
}

// ---------------- output projection: out[M,10] = h[M,128] @ Wo[128,10] + bo ----------------

__global__ __launch_bounds__(256) void out_gemm(const float* __restrict__ h,
                                                const float* __restrict__ Wo,
                                                const float* __restrict__ bo,
                                                float* __restrict__ out) {
    __shared__ float Ws[HID * OUT_DIM];
    for (int i = threadIdx.x; i < HID * OUT_DIM; i += 256) Ws[i] = Wo[i];
    __syncthreads();
    int gid = blockIdx.x * blockDim.x + threadIdx.x;
    if (gid >= N_NODES * OUT_DIM) return;
    int n = gid / OUT_DIM;
    int c = gid - n * OUT_DIM;
    const float* hr = h + (size_t)n * HID;
    float s = 0.f;
    #pragma unroll 4
    for (int k = 0; k < HID; ++k) s += hr[k] * Ws[k * OUT_DIM + c];
    out[gid] = s + bo[c];
}

// ---------------- launch ----------------

extern "C" void kernel_launch(void* const* d_in, const int* in_sizes, int n_in,
                              void* d_out, int out_size, void* d_ws, size_t ws_size,
                              hipStream_t stream) {
    const float* x     = (const float*)d_in[0];
    const int*   ei    = (const int*)d_in[1];
    const int*   src   = ei;
    const int*   dst   = ei + N_EDGES;
    const float* W_in  = (const float*)d_in[2];
    const float* b_in  = (const float*)d_in[3];
    const float* Wc    = (const float*)d_in[4];
    const float* bc    = (const float*)d_in[5];
    const float* gamma = (const float*)d_in[6];
    const float* beta  = (const float*)d_in[7];
    const float* W_out = (const float*)d_in[8];
    const float* b_out = (const float*)d_in[9];
    float* out = (float*)d_out;

    char* p = (char*)d_ws;
    auto alloc = [&](size_t bytes) -> char* {
        char* q = p;
        p += (bytes + 255) & ~(size_t)255;
        return q;
    };
    float*  A         = (float*)alloc(sizeof(float) * N_NODES * HID);   // current h (also residual)
    uint32* B16       = (uint32*)alloc(sizeof(unsigned short) * N_NODES * HID);  // bf16 messages
    float*  C         = (float*)alloc(sizeof(float) * N_NODES * HID);   // aggregated
    float*  dinv      = (float*)alloc(sizeof(float) * N_NODES);
    int*    deg_cnt   = (int*)alloc(sizeof(int) * (N_NODES + 1));       // last int = cursor
    int*    cursor    = deg_cnt + N_NODES;
    int*    row_start = (int*)alloc(sizeof(int) * N_NODES);
    int*    fill_ptr  = (int*)alloc(sizeof(int) * N_NODES);
    int*    col_src   = (int*)alloc(sizeof(int) * N_EDGES);
    float*  colsum    = (float*)alloc(sizeof(float) * 256);             // [0:128) sum, [128:256) sumsq
    float*  colsumsq  = colsum + 128;
    float*  scale     = (float*)alloc(sizeof(float) * 128);
    float*  shift     = (float*)alloc(sizeof(float) * 128);

    // CSR build: count -> per-wave atomic range assignment -> fill
    hipMemsetAsync(deg_cnt, 0, sizeof(int) * (N_NODES + 1), stream);
    count_kernel<<<(N_EDGES + 255) / 256, 256, 0, stream>>>(dst, deg_cnt);
    assign_kernel<<<(N_NODES + 255) / 256, 256, 0, stream>>>(deg_cnt, row_start, fill_ptr, dinv, cursor);
    fill_kernel<<<(N_EDGES + 255) / 256, 256, 0, stream>>>(src, dst, fill_ptr, col_src);

    // input projection + relu (fp32 out)
    gemm128<1, 0><<<(N_NODES + 63) / 64, 256, 0, stream>>>(x, W_in, b_in, nullptr, A, N_NODES, IN_DIM);

    for (int l = 0; l < 3; ++l) {
        // h @ Wc, row-scaled by dinv, bf16 out
        gemm128<0, 1><<<(N_NODES + 63) / 64, 256, 0, stream>>>(A, Wc + l * HID * HID, nullptr, dinv, B16, N_NODES, HID);
        agg_kernel<<<N_NODES / 4, dim3(64, 4), 0, stream>>>(B16, dinv, row_start, deg_cnt, col_src, bc + l * HID, C);
        hipMemsetAsync(colsum, 0, sizeof(float) * 256, stream);
        stats_kernel<<<500, 256, 0, stream>>>(C, colsum, colsumsq);
        finalize_bn<<<1, 128, 0, stream>>>(colsum, colsumsq, gamma + l * HID, beta + l * HID, scale, shift);
        if (l == 0) apply_bn<0><<<N_NODES * HID / 4 / 256, 256, 0, stream>>>(C, scale, shift, A);
        else        apply_bn<1><<<N_NODES * HID / 4 / 256, 256, 0, stream>>>(C, scale, shift, A);
    }

    out_gemm<<<(N_NODES * OUT_DIM + 255) / 256, 256, 0, stream>>>(A, W_out, b_out, out);
}

// Round 5
// 474.617 us; speedup vs baseline: 1.9029x; 1.1369x over previous
//
#include <hip/hip_runtime.h>

#define N_NODES 50000
#define N_EDGES 600000
#define IN_DIM 256
#define HID 128
#define OUT_DIM 10
#define BN_EPS 1e-5f

typedef unsigned int uint32;
typedef __attribute__((ext_vector_type(8))) short short8;   // 8 bf16 = 4 VGPRs
typedef __attribute__((ext_vector_type(4))) float float4v;  // MFMA acc

__device__ __forceinline__ unsigned short f2bf_rne(float f) {
    uint32 u = __float_as_uint(f);
    u += 0x7FFF + ((u >> 16) & 1);          // round-to-nearest-even
    return (unsigned short)(u >> 16);
}

// ---------------- edge preprocessing: CSR by dst (no prefix scan needed) ----------------

__global__ void count_kernel(const int* __restrict__ dst, int* __restrict__ cnt) {
    int e = blockIdx.x * blockDim.x + threadIdx.x;
    if (e < N_EDGES) atomicAdd(&cnt[dst[e]], 1);
}

// Wave-64 inclusive scan of counts, one atomicAdd on a global cursor per wave.
// Ranges are contiguous & disjoint per dst; order across waves irrelevant.
__global__ __launch_bounds__(256) void assign_kernel(const int* __restrict__ cnt,
                                                     int* __restrict__ row_start,
                                                     int* __restrict__ fill_ptr,
                                                     float* __restrict__ dinv,
                                                     int* __restrict__ cursor) {
    int i = blockIdx.x * blockDim.x + threadIdx.x;
    int c = (i < N_NODES) ? cnt[i] : 0;
    int lane = threadIdx.x & 63;
    int v = c;
    #pragma unroll
    for (int off = 1; off < 64; off <<= 1) {
        int t = __shfl_up(v, off, 64);
        if (lane >= off) v += t;
    }
    int waveTotal = __shfl(v, 63, 64);
    int base = 0;
    if (lane == 63) base = atomicAdd(cursor, waveTotal);
    base = __shfl(base, 63, 64);
    if (i < N_NODES) {
        int start = base + v - c;
        row_start[i] = start;
        fill_ptr[i] = start;
        dinv[i] = rsqrtf((float)c + 1.0f);   // +1 self-loop
    }
}

__global__ void fill_kernel(const int* __restrict__ src, const int* __restrict__ dst,
                            int* __restrict__ fill_ptr, int* __restrict__ col_src) {
    int e = blockIdx.x * blockDim.x + threadIdx.x;
    if (e < N_EDGES) {
        int d = dst[e];
        int p = atomicAdd(&fill_ptr[d], 1);
        col_src[p] = src[e];
    }
}

// ---------------- weight pre-pack into MFMA B-fragment layout ----------------
// packedB[((kt*8+nt)*64 + lane)*8 + j] = bf16( W[kt*32 + (lane>>4)*8 + j][nt*16 + (lane&15)] )

__global__ void pack_w_kernel(const float* __restrict__ W, unsigned short* __restrict__ P, int K) {
    int idx = blockIdx.x * blockDim.x + threadIdx.x;     // (kt*8+nt)*64 + lane
    int total = (K / 32) * 8 * 64;
    if (idx >= total) return;
    int lane = idx & 63;
    int nt = (idx >> 6) & 7;
    int kt = idx >> 9;
    int n = nt * 16 + (lane & 15);
    int kbase = kt * 32 + (lane >> 4) * 8;
    unsigned short* dstp = P + (size_t)idx * 8;
    #pragma unroll
    for (int j = 0; j < 8; ++j) dstp[j] = f2bf_rne(W[(size_t)(kbase + j) * HID + n]);
}

// ---------------- MFMA bf16 GEMM: out[M,128] = (A[M,K]@W) * rowscale (+bias)(+relu) ----------------
// block 256 = 4 waves; tile 64 rows x 128 cols; wave w -> rows w*16..w*16+15.
// A fp32 staged -> bf16 LDS (stride 40 shorts = 80 B: 2-way bank aliasing, free).
// B pre-packed fragments from global (L2-resident).
// MFMA mappings (m89-verified): A[m=lane&15][k=quad*8+j]; D: col=lane&15, row=quad*4+reg.

template <int K, int RELU, int OUTBF16>
__global__ __launch_bounds__(256) void gemm_mfma(const float* __restrict__ A,
                                                 const unsigned short* __restrict__ PB,
                                                 const float* __restrict__ bias,
                                                 const float* __restrict__ rowscale,
                                                 void* __restrict__ out_v, int M) {
    __shared__ unsigned short As[64 * 40];
    int tid = threadIdx.x;
    int w = tid >> 6, lane = tid & 63;
    int mrow = lane & 15, quad = lane >> 4;
    int m0 = blockIdx.x * 64;

    float4v acc[8];
    #pragma unroll
    for (int nt = 0; nt < 8; ++nt)
        #pragma unroll
        for (int i = 0; i < 4; ++i) acc[nt][i] = 0.f;

    int r = tid >> 2;        // 0..63: staging row
    int cq = tid & 3;        // col quarter (8 floats)

    for (int kt = 0; kt < K / 32; ++kt) {
        // ---- stage A 64x32 fp32 -> bf16 LDS ----
        short8 pk;
        if (m0 + r < M) {
            const float* srcp = A + (size_t)(m0 + r) * K + kt * 32 + cq * 8;
            float4 a0 = *(const float4*)(srcp);
            float4 a1 = *(const float4*)(srcp + 4);
            pk[0] = (short)f2bf_rne(a0.x); pk[1] = (short)f2bf_rne(a0.y);
            pk[2] = (short)f2bf_rne(a0.z); pk[3] = (short)f2bf_rne(a0.w);
            pk[4] = (short)f2bf_rne(a1.x); pk[5] = (short)f2bf_rne(a1.y);
            pk[6] = (short)f2bf_rne(a1.z); pk[7] = (short)f2bf_rne(a1.w);
        } else {
            #pragma unroll
            for (int j = 0; j < 8; ++j) pk[j] = 0;
        }
        __syncthreads();                       // protect previous iteration's reads
        *(short8*)&As[r * 40 + cq * 8] = pk;
        __syncthreads();

        // ---- A fragment ----
        short8 afrag = *(const short8*)&As[(w * 16 + mrow) * 40 + quad * 8];

        // ---- 8 B fragments + MFMAs ----
        const unsigned short* pb = PB + ((size_t)(kt * 8) * 64 + lane) * 8;
        #pragma unroll
        for (int nt = 0; nt < 8; ++nt) {
            short8 bfrag = *(const short8*)(pb + (size_t)nt * 64 * 8);
            acc[nt] = __builtin_amdgcn_mfma_f32_16x16x32_bf16(afrag, bfrag, acc[nt], 0, 0, 0);
        }
    }

    // ---- epilogue: row = m0 + w*16 + quad*4 + reg, col = nt*16 + mrow ----
    int rowbase = m0 + w * 16 + quad * 4;
    float rs[4];
    #pragma unroll
    for (int reg = 0; reg < 4; ++reg) {
        int row = rowbase + reg;
        rs[reg] = (rowscale && row < M) ? rowscale[row] : 1.0f;
    }
    #pragma unroll
    for (int nt = 0; nt < 8; ++nt) {
        int col = nt * 16 + mrow;
        float bv = bias ? bias[col] : 0.f;
        #pragma unroll
        for (int reg = 0; reg < 4; ++reg) {
            int row = rowbase + reg;
            if (row < M) {
                float o = acc[nt][reg] * rs[reg] + bv;
                if (RELU) o = fmaxf(o, 0.f);
                if (OUTBF16)
                    ((unsigned short*)out_v)[(size_t)row * HID + col] = f2bf_rne(o);
                else
                    ((float*)out_v)[(size_t)row * HID + col] = o;
            }
        }
    }
}

// ---------------- CSR pull aggregation (bf16 messages, one wave per node) ----------------
// Bs rows: 128 bf16 (256 B), pre-scaled by dinv[row].
// C[n][f] = dinv[n] * ( Bs[n][f] + sum_e Bs[src_e][f] ) + bc[f]

__global__ __launch_bounds__(256) void agg_kernel(const uint32* __restrict__ Bs32,  // [N][64] uints
                                                  const float* __restrict__ dinv,
                                                  const int* __restrict__ row_start,
                                                  const int* __restrict__ cnt,
                                                  const int* __restrict__ col_src,
                                                  const float* __restrict__ bc,
                                                  float* __restrict__ C) {
    int f2 = threadIdx.x;                       // 0..63
    int n = blockIdx.x * 4 + threadIdx.y;
    if (n >= N_NODES) return;

    uint32 vs = Bs32[(size_t)n * 64 + f2];      // self term
    float acc0 = __uint_as_float(vs << 16);
    float acc1 = __uint_as_float(vs & 0xFFFF0000u);

    int beg = row_start[n];
    int end = beg + cnt[n];
    int e = beg;
    for (; e + 4 <= end; e += 4) {
        int s0 = col_src[e + 0];
        int s1 = col_src[e + 1];
        int s2 = col_src[e + 2];
        int s3 = col_src[e + 3];
        uint32 v0 = Bs32[(size_t)s0 * 64 + f2];
        uint32 v1 = Bs32[(size_t)s1 * 64 + f2];
        uint32 v2 = Bs32[(size_t)s2 * 64 + f2];
        uint32 v3 = Bs32[(size_t)s3 * 64 + f2];
        acc0 += __uint_as_float(v0 << 16);
        acc1 += __uint_as_float(v0 & 0xFFFF0000u);
        acc0 += __uint_as_float(v1 << 16);
        acc1 += __uint_as_float(v1 & 0xFFFF0000u);
        acc0 += __uint_as_float(v2 << 16);
        acc1 += __uint_as_float(v2 & 0xFFFF0000u);
        acc0 += __uint_as_float(v3 << 16);
        acc1 += __uint_as_float(v3 & 0xFFFF0000u);
    }
    for (; e < end; ++e) {
        int s = col_src[e];
        uint32 v = Bs32[(size_t)s * 64 + f2];
        acc0 += __uint_as_float(v << 16);
        acc1 += __uint_as_float(v & 0xFFFF0000u);
    }

    float di = dinv[n];
    float2 bcv = *(const float2*)(bc + f2 * 2);
    float2 o;
    o.x = acc0 * di + bcv.x;
    o.y = acc1 * di + bcv.y;
    *(float2*)(C + (size_t)n * HID + f2 * 2) = o;
}

// ---------------- BN stats / finalize / apply ----------------

__global__ __launch_bounds__(256) void stats_kernel(const float* __restrict__ C,
                                                    float* __restrict__ colsum,
                                                    float* __restrict__ colsumsq) {
    __shared__ float sh[512];
    int f = threadIdx.x & 127;
    int g = threadIdx.x >> 7;
    int r0 = blockIdx.x * 100;
    float s = 0.f, sq = 0.f;
    for (int r = g; r < 100; r += 2) {
        float v = C[(size_t)(r0 + r) * HID + f];
        s += v; sq += v * v;
    }
    sh[threadIdx.x] = s;
    sh[256 + threadIdx.x] = sq;
    __syncthreads();
    if (threadIdx.x < 128) {
        s = sh[threadIdx.x] + sh[threadIdx.x + 128];
        sq = sh[256 + threadIdx.x] + sh[256 + threadIdx.x + 128];
        atomicAdd(&colsum[f], s);
        atomicAdd(&colsumsq[f], sq);
    }
}

__global__ void finalize_bn(const float* __restrict__ colsum, const float* __restrict__ colsumsq,
                            const float* __restrict__ gamma, const float* __restrict__ beta,
                            float* __restrict__ scale, float* __restrict__ shift) {
    int f = threadIdx.x;
    float mu = colsum[f] * (1.0f / N_NODES);
    float var = colsumsq[f] * (1.0f / N_NODES) - mu * mu;
    float rstd = rsqrtf(var + BN_EPS);
    float sc = rstd * gamma[f];
    scale[f] = sc;
    shift[f] = beta[f] - mu * sc;
}

template <int RES>
__global__ __launch_bounds__(256) void apply_bn(const float* __restrict__ C,
                                                const float* __restrict__ scale,
                                                const float* __restrict__ shift,
                                                float* __restrict__ A) {
    int idx = blockIdx.x * blockDim.x + threadIdx.x;   // float4 index
    const int total = N_NODES * HID / 4;
    if (idx >= total) return;
    int fq = idx & 31;                                  // 32 float4 per row
    float4 c = ((const float4*)C)[idx];
    float4 sc = ((const float4*)scale)[fq];
    float4 sh = ((const float4*)shift)[fq];
    float4 h;
    h.x = fmaxf(c.x * sc.x + sh.x, 0.f);
    h.y = fmaxf(c.y * sc.y + sh.y, 0.f);
    h.z = fmaxf(c.z * sc.z + sh.z, 0.f);
    h.w = fmaxf(c.w * sc.w + sh.w, 0.f);
    if (RES) {
        float4 a = ((const float4*)A)[idx];
        h.x += a.x; h.y += a.y; h.z += a.z; h.w += a.w;
    }
    ((float4*)A)[idx] = h;
}

// ---------------- output projection: out[M,10] = h[M,128] @ Wo[128,10] + bo ----------------

__global__ __launch_bounds__(256) void out_gemm(const float* __restrict__ h,
                                                const float* __restrict__ Wo,
                                                const float* __restrict__ bo,
                                                float* __restrict__ out) {
    __shared__ float Ws[HID * OUT_DIM];
    for (int i = threadIdx.x; i < HID * OUT_DIM; i += 256) Ws[i] = Wo[i];
    __syncthreads();
    int gid = blockIdx.x * blockDim.x + threadIdx.x;
    if (gid >= N_NODES * OUT_DIM) return;
    int n = gid / OUT_DIM;
    int c = gid - n * OUT_DIM;
    const float* hr = h + (size_t)n * HID;
    float s = 0.f;
    #pragma unroll 4
    for (int k = 0; k < HID; ++k) s += hr[k] * Ws[k * OUT_DIM + c];
    out[gid] = s + bo[c];
}

// ---------------- launch ----------------

extern "C" void kernel_launch(void* const* d_in, const int* in_sizes, int n_in,
                              void* d_out, int out_size, void* d_ws, size_t ws_size,
                              hipStream_t stream) {
    const float* x     = (const float*)d_in[0];
    const int*   ei    = (const int*)d_in[1];
    const int*   src   = ei;
    const int*   dst   = ei + N_EDGES;
    const float* W_in  = (const float*)d_in[2];
    const float* b_in  = (const float*)d_in[3];
    const float* Wc    = (const float*)d_in[4];
    const float* bc    = (const float*)d_in[5];
    const float* gamma = (const float*)d_in[6];
    const float* beta  = (const float*)d_in[7];
    const float* W_out = (const float*)d_in[8];
    const float* b_out = (const float*)d_in[9];
    float* out = (float*)d_out;

    char* p = (char*)d_ws;
    auto alloc = [&](size_t bytes) -> char* {
        char* q = p;
        p += (bytes + 255) & ~(size_t)255;
        return q;
    };
    float*  A         = (float*)alloc(sizeof(float) * N_NODES * HID);   // current h (also residual)
    uint32* B16       = (uint32*)alloc(sizeof(unsigned short) * N_NODES * HID);  // bf16 messages
    float*  C         = (float*)alloc(sizeof(float) * N_NODES * HID);   // aggregated
    float*  dinv      = (float*)alloc(sizeof(float) * N_NODES);
    int*    deg_cnt   = (int*)alloc(sizeof(int) * (N_NODES + 1));       // last int = cursor
    int*    cursor    = deg_cnt + N_NODES;
    int*    row_start = (int*)alloc(sizeof(int) * N_NODES);
    int*    fill_ptr  = (int*)alloc(sizeof(int) * N_NODES);
    int*    col_src   = (int*)alloc(sizeof(int) * N_EDGES);
    unsigned short* PWin = (unsigned short*)alloc(sizeof(unsigned short) * (IN_DIM / 32) * 8 * 64 * 8);
    unsigned short* PWc  = (unsigned short*)alloc(sizeof(unsigned short) * 3 * (HID / 32) * 8 * 64 * 8);
    float*  colsum    = (float*)alloc(sizeof(float) * 256);             // [0:128) sum, [128:256) sumsq
    float*  colsumsq  = colsum + 128;
    float*  scale     = (float*)alloc(sizeof(float) * 128);
    float*  shift     = (float*)alloc(sizeof(float) * 128);

    // CSR build: count -> per-wave atomic range assignment -> fill
    hipMemsetAsync(deg_cnt, 0, sizeof(int) * (N_NODES + 1), stream);
    count_kernel<<<(N_EDGES + 255) / 256, 256, 0, stream>>>(dst, deg_cnt);
    assign_kernel<<<(N_NODES + 255) / 256, 256, 0, stream>>>(deg_cnt, row_start, fill_ptr, dinv, cursor);
    fill_kernel<<<(N_EDGES + 255) / 256, 256, 0, stream>>>(src, dst, fill_ptr, col_src);

    // pack weights into MFMA B-fragment layout (bf16)
    pack_w_kernel<<<(((IN_DIM / 32) * 8 * 64) + 255) / 256, 256, 0, stream>>>(W_in, PWin, IN_DIM);
    const int pwc_elems = (HID / 32) * 8 * 64;          // per layer
    for (int l = 0; l < 3; ++l)
        pack_w_kernel<<<(pwc_elems + 255) / 256, 256, 0, stream>>>(Wc + l * HID * HID,
                                                                   PWc + (size_t)l * pwc_elems * 8, HID);

    // input projection + relu (fp32 out)
    gemm_mfma<IN_DIM, 1, 0><<<(N_NODES + 63) / 64, 256, 0, stream>>>(x, PWin, b_in, nullptr, A, N_NODES);

    for (int l = 0; l < 3; ++l) {
        // h @ Wc, row-scaled by dinv, bf16 out
        gemm_mfma<HID, 0, 1><<<(N_NODES + 63) / 64, 256, 0, stream>>>(A, PWc + (size_t)l * pwc_elems * 8,
                                                                      nullptr, dinv, B16, N_NODES);
        agg_kernel<<<N_NODES / 4, dim3(64, 4), 0, stream>>>(B16, dinv, row_start, deg_cnt, col_src, bc + l * HID, C);
        hipMemsetAsync(colsum, 0, sizeof(float) * 256, stream);
        stats_kernel<<<500, 256, 0, stream>>>(C, colsum, colsumsq);
        finalize_bn<<<1, 128, 0, stream>>>(colsum, colsumsq, gamma + l * HID, beta + l * HID, scale, shift);
        if (l == 0) apply_bn<0><<<N_NODES * HID / 4 / 256, 256, 0, stream>>>(C, scale, shift, A);
        else        apply_bn<1><<<N_NODES * HID / 4 / 256, 256, 0, stream>>>(C, scale, shift, A);
    }

    out_gemm<<<(N_NODES * OUT_DIM + 255) / 256, 256, 0, stream>>>(A, W_out, b_out, out);
}